// Round 2
// baseline (992.001 us; speedup 1.0000x reference)
//
#include <hip/hip_runtime.h>

// ---------------------------------------------------------------------------
// GCN 2-layer inference on MI355X — round 2: scatter->gather via per-call CSR.
// F0=512, F1=16, F2=7 (padded to 8).
// ---------------------------------------------------------------------------

#define F0 512
#define F1 16
#define F2 7

static __device__ __forceinline__ void atomAddF(float* p, float v) {
    unsafeAtomicAdd(p, v);  // global_atomic_add_f32, no CAS loop
}

// Detect int64 vs int32 edge_index (odd int32 slots all zero => int64 LE).
__global__ void k_detect(const int* __restrict__ ei32, int twoE, int* __restrict__ flag) {
    int t = threadIdx.x;
    int idx = 1 + 2 * t;
    int v = (idx < twoE) ? ei32[idx] : 0;
    unsigned long long b = __ballot(v != 0);
    if (t == 0) *flag = (b == 0ULL) ? 1 : 0;
}

__global__ void k_init(float* __restrict__ deg, int* __restrict__ cnt, int n) {
    int i = blockIdx.x * blockDim.x + threadIdx.x;
    if (i < n) { deg[i] = 1.0f; cnt[i] = 0; }   // deg starts at self-loop weight
}

// Weighted in-degree + edge-count histogram (by dst).
__global__ void k_deg(const int* __restrict__ ei32, const long long* __restrict__ ei64,
                      const int* __restrict__ flag, const float* __restrict__ w,
                      float* __restrict__ deg, int* __restrict__ cnt, int E) {
    int e = blockIdx.x * blockDim.x + threadIdx.x;
    if (e >= E) return;
    int dst = (*flag) ? (int)ei64[(size_t)E + e] : ei32[(size_t)E + e];
    atomAddF(&deg[dst], w[e]);
    atomicAdd(&cnt[dst], 1);
}

__global__ void k_dinv(float* __restrict__ deg, int n) {
    int i = blockIdx.x * blockDim.x + threadIdx.x;
    if (i < n) {
        float d = deg[i];
        deg[i] = (d > 0.f) ? rsqrtf(d) : 0.f;
    }
}

// ---- 3-pass exclusive scan of cnt[n] -> rowptr[n+1], cursor[n] -------------
__global__ __launch_bounds__(256) void k_scanA(const int* __restrict__ cnt,
                                               int* __restrict__ bsum, int n) {
    __shared__ int s[256];
    int t = threadIdx.x, i = blockIdx.x * 256 + t;
    int v = (i < n) ? cnt[i] : 0;
    s[t] = v; __syncthreads();
    for (int off = 128; off > 0; off >>= 1) {
        if (t < off) s[t] += s[t + off];
        __syncthreads();
    }
    if (t == 0) bsum[blockIdx.x] = s[0];
}

__global__ __launch_bounds__(512) void k_scanB(int* __restrict__ bsum, int nb) {
    __shared__ int s[512];
    int t = threadIdx.x;
    int v = (t < nb) ? bsum[t] : 0;
    s[t] = v; __syncthreads();
    for (int off = 1; off < 512; off <<= 1) {
        int tv = (t >= off) ? s[t - off] : 0;
        __syncthreads();
        s[t] += tv;
        __syncthreads();
    }
    if (t < nb) bsum[t] = s[t] - v;      // exclusive
}

__global__ __launch_bounds__(256) void k_scanC(const int* __restrict__ cnt,
                                               const int* __restrict__ bsum,
                                               int* __restrict__ rowptr,
                                               int* __restrict__ cursor, int n, int E) {
    __shared__ int s[256];
    int t = threadIdx.x, i = blockIdx.x * 256 + t;
    int v = (i < n) ? cnt[i] : 0;
    s[t] = v; __syncthreads();
    for (int off = 1; off < 256; off <<= 1) {
        int tv = (t >= off) ? s[t - off] : 0;
        __syncthreads();
        s[t] += tv;
        __syncthreads();
    }
    if (i < n) {
        int excl = s[t] - v + bsum[blockIdx.x];
        rowptr[i] = excl;
        cursor[i] = excl;
        if (i == n - 1) rowptr[n] = E;
    }
}

// Reorder edges into dst-CSR; payload = (src, norm-bits) 8B.
__global__ void k_reorder(const int* __restrict__ ei32, const long long* __restrict__ ei64,
                          const int* __restrict__ flag, const float* __restrict__ w,
                          const float* __restrict__ dinv, int* __restrict__ cursor,
                          int2* __restrict__ pay, int E) {
    int e = blockIdx.x * blockDim.x + threadIdx.x;
    if (e >= E) return;
    int src, dst;
    if (*flag) { src = (int)ei64[e]; dst = (int)ei64[(size_t)E + e]; }
    else       { src = ei32[e];      dst = ei32[(size_t)E + e]; }
    float nm = dinv[src] * w[e] * dinv[dst];
    int pos = atomicAdd(&cursor[dst], 1);
    pay[pos] = make_int2(src, __float_as_int(nm));
}

// h1 = x @ W1  (16 rows/block, thread (r,j) -> h1[row][j])
#define PW 516
__global__ __launch_bounds__(256) void k_gemm1(
        const float* __restrict__ x, const float* __restrict__ W1,
        float* __restrict__ h1, int n) {
    __shared__ float Wt[F1 * PW];
    int t = threadIdx.x;
    for (int idx = t; idx < F0 * F1; idx += 256) {
        int k = idx >> 4, j = idx & 15;
        Wt[j * PW + k] = W1[idx];
    }
    __syncthreads();
    int r = t >> 4, j = t & 15;
    int row = blockIdx.x * 16 + r;
    if (row >= n) return;
    const float4* xr = (const float4*)(x + (size_t)row * F0);
    const float4* wr = (const float4*)(Wt + j * PW);
    float acc = 0.f;
#pragma unroll 8
    for (int k4 = 0; k4 < F0 / 4; ++k4) {
        float4 xv = xr[k4];
        float4 wv = wr[k4];
        acc += xv.x * wv.x + xv.y * wv.y + xv.z * wv.z + xv.w * wv.w;
    }
    h1[(size_t)row * F1 + j] = acc;
}

// Layer-1 aggregate (gather): acc1[row][j] = relu(dinv^2*h1[row][j] + b1[j] + sum_e nm*h1[src][j])
__global__ __launch_bounds__(256) void k_agg1(
        const int* __restrict__ rowptr, const int2* __restrict__ pay,
        const float* __restrict__ h1, const float* __restrict__ dinv,
        const float* __restrict__ b1, float* __restrict__ acc1, int n) {
    int t = threadIdx.x;
    int r = t >> 4, j = t & 15;
    int row = blockIdx.x * 16 + r;
    if (row >= n) return;
    int p0 = rowptr[row], p1 = rowptr[row + 1];
    float acc = 0.f;
    for (int p = p0; p < p1; ++p) {
        int2 pr = pay[p];                      // broadcast across 16 lanes
        float nm = __int_as_float(pr.y);
        acc += nm * h1[(size_t)pr.x * F1 + j]; // coalesced 64B gather
    }
    float di = dinv[row];
    float v = di * di * h1[(size_t)row * F1 + j] + b1[j] + acc;
    acc1[(size_t)row * F1 + j] = fmaxf(v, 0.f);
}

// h2 = acc1 @ W2 (acc1 already relu'd), padded to 8 cols with 0.
__global__ __launch_bounds__(256) void k_layer2(
        const float* __restrict__ acc1, const float* __restrict__ W2,
        float* __restrict__ h2, int n) {
    __shared__ float sW[F1 * F2];
    int t = threadIdx.x;
    if (t < F1 * F2) sW[t] = W2[t];
    __syncthreads();
    int i = blockIdx.x * 256 + t;
    if (i >= n) return;
    const float4* a4 = (const float4*)(acc1 + (size_t)i * F1);
    float4 v0 = a4[0], v1 = a4[1], v2 = a4[2], v3 = a4[3];
    float g[F1] = {v0.x, v0.y, v0.z, v0.w, v1.x, v1.y, v1.z, v1.w,
                   v2.x, v2.y, v2.z, v2.w, v3.x, v3.y, v3.z, v3.w};
    float h[8];
#pragma unroll
    for (int c = 0; c < F2; ++c) {
        float s = 0.f;
#pragma unroll
        for (int jj = 0; jj < F1; ++jj) s += g[jj] * sW[jj * F2 + c];
        h[c] = s;
    }
    h[7] = 0.f;
    ((float4*)(h2 + (size_t)i * 8))[0] = make_float4(h[0], h[1], h[2], h[3]);
    ((float4*)(h2 + (size_t)i * 8))[1] = make_float4(h[4], h[5], h[6], 0.f);
}

// Layer-2 aggregate + bias + log_softmax, fused. 8 threads per node.
__global__ __launch_bounds__(256) void k_agg2(
        const int* __restrict__ rowptr, const int2* __restrict__ pay,
        const float* __restrict__ h2, const float* __restrict__ dinv,
        const float* __restrict__ b2, float* __restrict__ out, int n) {
    __shared__ float sb[8];
    int t = threadIdx.x;
    if (t < F2) sb[t] = b2[t];
    if (t == F2) sb[7] = 0.f;
    __syncthreads();
    int r = t >> 3, c = t & 7;
    int row = blockIdx.x * 32 + r;
    if (row >= n) return;
    int p0 = rowptr[row], p1 = rowptr[row + 1];
    float acc = 0.f;
    for (int p = p0; p < p1; ++p) {
        int2 pr = pay[p];
        float nm = __int_as_float(pr.y);
        acc += nm * h2[(size_t)pr.x * 8 + c];  // coalesced 32B gather
    }
    float di = dinv[row];
    float v = di * di * h2[(size_t)row * 8 + c] + sb[c] + acc;
    // log_softmax over the 8-lane group (lane 7 masked out)
    float m = (c < F2) ? v : -1e30f;
#pragma unroll
    for (int mask = 1; mask < 8; mask <<= 1)
        m = fmaxf(m, __shfl_xor(m, mask, 8));
    float e = (c < F2) ? __expf(v - m) : 0.f;
    float s = e;
#pragma unroll
    for (int mask = 1; mask < 8; mask <<= 1)
        s += __shfl_xor(s, mask, 8);
    float ls = __logf(s) + m;
    if (c < F2) out[(size_t)row * F2 + c] = v - ls;
}

extern "C" void kernel_launch(void* const* d_in, const int* in_sizes, int n_in,
                              void* d_out, int out_size, void* d_ws, size_t ws_size,
                              hipStream_t stream) {
    const float* x  = (const float*)d_in[0];
    const int* ei32 = (const int*)d_in[1];
    const long long* ei64 = (const long long*)d_in[1];
    const float* w  = (const float*)d_in[2];
    const float* W1 = (const float*)d_in[3];
    const float* b1 = (const float*)d_in[4];
    const float* W2 = (const float*)d_in[5];
    const float* b2 = (const float*)d_in[6];
    float* out = (float*)d_out;

    const int n = in_sizes[0] / F0;       // 100000
    const int E = in_sizes[2];            // 3200000
    const int nb = (n + 255) / 256;       // scan blocks (391)

    // workspace layout (4-byte units; pay needs 8B alignment — offsets even)
    float* ws   = (float*)d_ws;
    float* deg  = ws;                           // n (becomes dinv)
    float* h1   = deg + n;                      // 16n (reused as h2: 8n)
    float* acc1 = h1 + (size_t)n * F1;          // 16n
    int2* pay   = (int2*)(acc1 + (size_t)n * F1); // E int2 (33n dwords offset: even)
    int* rowptr = (int*)(pay + E);              // n+1
    int* cursor = rowptr + (n + 1);             // n
    int* cnt    = cursor + n;                   // n
    int* bsum   = cnt + n;                      // 512
    int* flag   = bsum + 512;                   // 1
    float* h2   = h1;                           // overlay (h1 dead after k_agg1)

    const int B = 256;
    k_detect<<<1, 64, 0, stream>>>(ei32, 2 * E, flag);
    k_init<<<(n + B - 1) / B, B, 0, stream>>>(deg, cnt, n);
    k_deg<<<(E + B - 1) / B, B, 0, stream>>>(ei32, ei64, flag, w, deg, cnt, E);
    k_dinv<<<(n + B - 1) / B, B, 0, stream>>>(deg, n);
    k_scanA<<<nb, B, 0, stream>>>(cnt, bsum, n);
    k_scanB<<<1, 512, 0, stream>>>(bsum, nb);
    k_scanC<<<nb, B, 0, stream>>>(cnt, bsum, rowptr, cursor, n, E);
    k_reorder<<<(E + B - 1) / B, B, 0, stream>>>(ei32, ei64, flag, w, deg, cursor, pay, E);
    k_gemm1<<<(n + 15) / 16, B, 0, stream>>>(x, W1, h1, n);
    k_agg1<<<(n + 15) / 16, B, 0, stream>>>(rowptr, pay, h1, deg, b1, acc1, n);
    k_layer2<<<(n + B - 1) / B, B, 0, stream>>>(acc1, W2, h2, n);
    k_agg2<<<(n + 31) / 32, B, 0, stream>>>(rowptr, pay, h2, deg, b2, out, n);
}